// Round 10
// baseline (185.554 us; speedup 1.0000x reference)
//
#include <hip/hip_runtime.h>
#include <hip/hip_bf16.h>

#define N 8192
#define D 512
#define K_TOP 12
#define THETA 10.0f
#define EPS 1e-8f
#define NSLICE 16
#define SLICE_J 512    // 4 j-tiles of 128 per block
#define TAU 0.10f      // candidate threshold; spill+fallback guarantee the guard
#define CAPL 16        // per-row per-block LDS cap (overflow -> exact global spill)
#define CAPG 192       // per-row global candidate cap

typedef float f32x16 __attribute__((ext_vector_type(16)));

__device__ __forceinline__ unsigned int bf16_bits_rne(float v) {
    unsigned int u = __float_as_uint(v);
    u += 0x7FFFu + ((u >> 16) & 1u);
    return u >> 16;
}

// async global->LDS DMA, 16B per lane; LDS dest is wave-uniform base + lane*16
__device__ __forceinline__ void load16(const unsigned char* g, unsigned char* l) {
    __builtin_amdgcn_global_load_lds(
        (const __attribute__((address_space(1))) unsigned int*)g,
        (__attribute__((address_space(3))) unsigned int*)l, 16, 0, 0);
}

// -- Kernel 0: row norms -> fp8 e4m3 normalized copy + norms + zero counters --
__global__ __launch_bounds__(256) void norm_kernel(const float* __restrict__ h,
                                                   unsigned char* __restrict__ hq,
                                                   float* __restrict__ norms,
                                                   int* __restrict__ gcnt,
                                                   int* __restrict__ gflag) {
    int row = blockIdx.x * 4 + (threadIdx.x >> 6);
    int lane = threadIdx.x & 63;
    const float4* hr = (const float4*)(h + (size_t)row * D);
    float4 p0 = hr[lane * 2], p1 = hr[lane * 2 + 1];
    float ss = p0.x * p0.x + p0.y * p0.y + p0.z * p0.z + p0.w * p0.w +
               p1.x * p1.x + p1.y * p1.y + p1.z * p1.z + p1.w * p1.w;
#pragma unroll
    for (int off = 32; off > 0; off >>= 1) ss += __shfl_xor(ss, off, 64);
    float nrm = fmaxf(sqrtf(ss), EPS);
    float inv = 1.0f / nrm;
    if (lane == 0) { gcnt[row] = 0; gflag[row] = 0; norms[row] = nrm; }
    unsigned int w0 = __builtin_amdgcn_cvt_pk_fp8_f32(p0.x * inv, p0.y * inv, 0, false);
    w0 = __builtin_amdgcn_cvt_pk_fp8_f32(p0.z * inv, p0.w * inv, w0, true);
    unsigned int w1 = __builtin_amdgcn_cvt_pk_fp8_f32(p1.x * inv, p1.y * inv, 0, false);
    w1 = __builtin_amdgcn_cvt_pk_fp8_f32(p1.z * inv, p1.w * inv, w1, true);
    ((uint2*)(hq + (size_t)row * D))[lane] = make_uint2(w0, w1);
}

// -- Kernel 1: fp8 MFMA, A-tile in REGISTERS, B-only LDS staging --
// grid (64,16) = 1024 blocks = 2/CU. Per wave: A frags = 128 VGPRs loaded
// once (L2-resident hq); per round stage one 16 KB B-slice (K=128), raw
// s_barrier + vmcnt(4) pipeline. ks/kk fully unrolled so Areg idx is static.
__global__ __launch_bounds__(256, 2) void simfp8_kernel(
        const unsigned char* __restrict__ hq,
        unsigned int* __restrict__ gcand,
        int* __restrict__ gcnt,
        int* __restrict__ gflag) {
    __shared__ unsigned char btiles[2][128 * 128];  // 32 KB
    __shared__ int cnt[128];
    __shared__ unsigned int lbuf[128][CAPL];

    const int i0 = blockIdx.x * 128;
    const int sl = blockIdx.y;
    const int t = threadIdx.x;
    const int wave = t >> 6, lane = t & 63;
    const int wr = (wave >> 1) * 64, wc = (wave & 1) * 64;
    const int lm32 = lane & 31, lg2 = lane >> 5;
    const int cb = lm32 & 7;  // read-side swizzle key (row&7 == lm32&7)

    // staging: B tile = 128 rows x 128 B; 16B chunk c = e*256 + t;
    // row = c>>3 = (t>>3)+e*32, slot = t&7, source chunk q = slot ^ (row&7)
    const int srow = t >> 3;
    const int sq = (t & 7) ^ (srow & 7);

    if (t < 128) cnt[t] = 0;   // published by first barrier pair

    auto issue = [&](int r) {
        int sel = r & 1;
        int jtn = r >> 2, ksn = r & 3;
        const unsigned char* gB =
            hq + (size_t)(sl * SLICE_J + jtn * 128 + srow) * D + ksn * 128 + sq * 16;
        unsigned char* lB = &btiles[sel][t * 16];
#pragma unroll
        for (int e = 0; e < 4; e++)
            load16(gB + (size_t)(e * 32) * D, lB + e * 4096);
    };

    issue(0);   // B0 in flight first (FIFO: B0, then A, then B1)

    // A fragments in registers: row = i0 + wr + x*32 + lm32,
    // K16-step g: bytes g*16 + lg2*8 .. +8  (per-lane 256 B per x)
    long long Areg[2][32];
    {
        const unsigned char* a0 = hq + (size_t)(i0 + wr + lm32) * D + lg2 * 8;
        const unsigned char* a1 = hq + (size_t)(i0 + wr + 32 + lm32) * D + lg2 * 8;
#pragma unroll
        for (int g = 0; g < 32; g++) {
            Areg[0][g] = *(const long long*)(a0 + g * 16);
            Areg[1][g] = *(const long long*)(a1 + g * 16);
        }
    }

    f32x16 acc[2][2];

    for (int jt = 0; jt < 4; jt++) {
        const int j0 = sl * SLICE_J + jt * 128;
#pragma unroll
        for (int ks = 0; ks < 4; ks++) {
            const int sel = ks & 1;          // (jt*4+ks)&1 == ks&1
            const int r = jt * 4 + ks;

            __builtin_amdgcn_s_barrier();    // prior reads of buffer sel done
            if (r < 15) {
                issue(r + 1);
                // FIFO drain: at r=0 this also drains the 64 A-loads
                asm volatile("s_waitcnt vmcnt(4)" ::: "memory");
            } else {
                asm volatile("s_waitcnt vmcnt(0)" ::: "memory");
            }
            __builtin_amdgcn_s_barrier();    // round r's B fully in LDS

            if (ks == 0) {
#pragma unroll
                for (int x = 0; x < 2; x++)
#pragma unroll
                    for (int y = 0; y < 2; y++)
#pragma unroll
                        for (int q = 0; q < 16; q++) acc[x][y][q] = 0.f;
            }

#pragma unroll
            for (int kk = 0; kk < 8; kk++) {
                const int g = ks * 8 + kk;   // static Areg index
                const int kb = ((kk ^ cb) << 4) + lg2 * 8;
                long long b0 = *(const long long*)&btiles[sel][(wc + lm32) * 128 + kb];
                long long b1 = *(const long long*)&btiles[sel][(wc + 32 + lm32) * 128 + kb];
                acc[0][0] = __builtin_amdgcn_mfma_f32_32x32x16_fp8_fp8(
                    Areg[0][g], b0, acc[0][0], 0, 0, 0);
                acc[0][1] = __builtin_amdgcn_mfma_f32_32x32x16_fp8_fp8(
                    Areg[0][g], b1, acc[0][1], 0, 0, 0);
                acc[1][0] = __builtin_amdgcn_mfma_f32_32x32x16_fp8_fp8(
                    Areg[1][g], b0, acc[1][0], 0, 0, 0);
                acc[1][1] = __builtin_amdgcn_mfma_f32_32x32x16_fp8_fp8(
                    Areg[1][g], b1, acc[1][1], 0, 0, 0);
            }

            if (ks == 3) {
                // 32x32 C/D: col=lane&31, row=(reg&3)+8*(reg>>2)+4*(lane>>5)
#pragma unroll
                for (int x = 0; x < 2; x++)
#pragma unroll
                    for (int y = 0; y < 2; y++) {
                        int gcol = j0 + wc + y * 32 + lm32;
#pragma unroll
                        for (int q = 0; q < 16; q++) {
                            int rr = wr + x * 32 + (q & 3) + 8 * (q >> 2) + 4 * lg2;
                            float v = acc[x][y][q];
                            if (i0 + rr == gcol) v = 1.0f;  // exact self-sim
                            if (v > TAU) {
                                unsigned int e =
                                    (bf16_bits_rne(v) << 16) | (unsigned int)gcol;
                                int idx = atomicAdd(&cnt[rr], 1);
                                if (idx < CAPL) lbuf[rr][idx] = e;
                                else {  // rare exact spill straight to global
                                    int grow = i0 + rr;
                                    int p = atomicAdd(&gcnt[grow], 1);
                                    if (p < CAPG) gcand[(size_t)grow * CAPG + p] = e;
                                    else gflag[grow] = 1;
                                }
                            }
                        }
                    }
            }
        }
    }

    __syncthreads();
    if (t < 128) {
        int c = cnt[t];
        int s = c < CAPL ? c : CAPL;
        if (s > 0) {
            int base = atomicAdd(&gcnt[i0 + t], s);
            unsigned int* dst = gcand + (size_t)(i0 + t) * CAPG;
            for (int k = 0; k < s; k++) {
                int p = base + k;
                if (p < CAPG) dst[p] = lbuf[t][k];
                else gflag[i0 + t] = 1;
            }
        }
    }
}

// -- Kernel 2: exact top-12 + softmax + gather (fp8 neighbors, fp32 self) --
__global__ __launch_bounds__(256) void gather_kernel(const float* __restrict__ h,
                                                     const unsigned char* __restrict__ hq,
                                                     const float* __restrict__ norms,
                                                     const unsigned int* __restrict__ gcand,
                                                     const int* __restrict__ gcnt,
                                                     const int* __restrict__ gflag,
                                                     float* __restrict__ out) {
    int row = blockIdx.x * 4 + (threadIdx.x >> 6);
    int lane = threadIdx.x & 63;
    int c = gcnt[row];

    float selv[K_TOP];
    int selj[K_TOP];

    if (c >= K_TOP && c <= CAPG && gflag[row] == 0) {
        const unsigned int* cr = gcand + (size_t)row * CAPG;
        unsigned int e[3];
#pragma unroll
        for (int q = 0; q < 3; q++) {
            int idx = lane + 64 * q;
            e[q] = (idx < c) ? cr[idx] : 0u;
        }
#pragma unroll
        for (int k = 0; k < K_TOP; k++) {
            unsigned int m = e[0];
            if (e[1] > m) m = e[1];
            if (e[2] > m) m = e[2];
#pragma unroll
            for (int off = 32; off > 0; off >>= 1) {
                unsigned int om = __shfl_xor(m, off, 64);
                if (om > m) m = om;
            }
            selv[k] = __uint_as_float(m & 0xFFFF0000u);
            selj[k] = (int)(m & 0x1FFFu);
#pragma unroll
            for (int q = 0; q < 3; q++)
                if (e[q] == m) e[q] = 0u;   // entries unique (distinct cols)
        }
    } else {
        // exact brute-force fallback over fp8 rows (rare; cheap insurance)
        float vals[K_TOP];
        int idxs[K_TOP];
#pragma unroll
        for (int q = 0; q < K_TOP; q++) { vals[q] = -3e38f; idxs[q] = 0; }
        float minv = -3e38f;
        int minp = 0;
        const unsigned int* rp = (const unsigned int*)(hq + (size_t)row * D);
        for (int col = lane; col < N; col += 64) {
            const unsigned int* cp = (const unsigned int*)(hq + (size_t)col * D);
            float s = 0.f;
            for (int k4 = 0; k4 < D / 4; k4++) {
                unsigned int ra = rp[k4], ca = cp[k4];
                s += __builtin_amdgcn_cvt_f32_fp8(ra, 0) * __builtin_amdgcn_cvt_f32_fp8(ca, 0);
                s += __builtin_amdgcn_cvt_f32_fp8(ra, 1) * __builtin_amdgcn_cvt_f32_fp8(ca, 1);
                s += __builtin_amdgcn_cvt_f32_fp8(ra, 2) * __builtin_amdgcn_cvt_f32_fp8(ca, 2);
                s += __builtin_amdgcn_cvt_f32_fp8(ra, 3) * __builtin_amdgcn_cvt_f32_fp8(ca, 3);
            }
            if (col == row) s = 1.0f;
            if (s > minv) {
                vals[minp] = s; idxs[minp] = col;
                minv = vals[0]; minp = 0;
#pragma unroll
                for (int q = 1; q < K_TOP; q++)
                    if (vals[q] < minv) { minv = vals[q]; minp = q; }
            }
        }
        for (int k = 0; k < K_TOP; k++) {
            float bv = vals[0]; int bp = 0;
#pragma unroll
            for (int q = 1; q < K_TOP; q++)
                if (vals[q] > bv) { bv = vals[q]; bp = q; }
            float v = bv; int j = idxs[bp]; int src = lane;
#pragma unroll
            for (int off = 32; off > 0; off >>= 1) {
                float ov = __shfl_xor(v, off, 64);
                int oj = __shfl_xor(j, off, 64);
                int os = __shfl_xor(src, off, 64);
                if (ov > v || (ov == v && os < src)) { v = ov; j = oj; src = os; }
            }
            selv[k] = __uint_as_float((unsigned int)(bf16_bits_rne(v) << 16));
            selj[k] = j;
            if (lane == src) vals[bp] = -3e38f;
        }
    }

    float mx = selv[0];
    float beta[K_TOP];
    float sum = 0.f;
#pragma unroll
    for (int q = 0; q < K_TOP; q++) { beta[q] = __expf(THETA * (selv[q] - mx)); sum += beta[q]; }
    float rs = 1.0f / sum;

    // lane owns output elements [lane*8, lane*8+8)
    float acc[8];
#pragma unroll
    for (int ee = 0; ee < 8; ee++) acc[ee] = 0.f;
#pragma unroll
    for (int q = 0; q < K_TOP; q++) {
        int j = selj[q];
        float w = beta[q] * rs;
        if (j == row) {   // wave-uniform; dominant term stays fp32-exact
            const float4* hr = (const float4*)(h + (size_t)row * D);
            float4 p0 = hr[lane * 2], p1 = hr[lane * 2 + 1];
            acc[0] += w * p0.x; acc[1] += w * p0.y; acc[2] += w * p0.z; acc[3] += w * p0.w;
            acc[4] += w * p1.x; acc[5] += w * p1.y; acc[6] += w * p1.z; acc[7] += w * p1.w;
        } else {          // neighbors (weight ~2e-4): fp8 row x norm
            float wj = w * norms[j];
            uint2 hv = ((const uint2*)(hq + (size_t)j * D))[lane];
            acc[0] += wj * __builtin_amdgcn_cvt_f32_fp8(hv.x, 0);
            acc[1] += wj * __builtin_amdgcn_cvt_f32_fp8(hv.x, 1);
            acc[2] += wj * __builtin_amdgcn_cvt_f32_fp8(hv.x, 2);
            acc[3] += wj * __builtin_amdgcn_cvt_f32_fp8(hv.x, 3);
            acc[4] += wj * __builtin_amdgcn_cvt_f32_fp8(hv.y, 0);
            acc[5] += wj * __builtin_amdgcn_cvt_f32_fp8(hv.y, 1);
            acc[6] += wj * __builtin_amdgcn_cvt_f32_fp8(hv.y, 2);
            acc[7] += wj * __builtin_amdgcn_cvt_f32_fp8(hv.y, 3);
        }
    }
    float4* orow = (float4*)(out + (size_t)row * D);
    orow[lane * 2] = make_float4(acc[0], acc[1], acc[2], acc[3]);
    orow[lane * 2 + 1] = make_float4(acc[4], acc[5], acc[6], acc[7]);
}

extern "C" void kernel_launch(void* const* d_in, const int* in_sizes, int n_in,
                              void* d_out, int out_size, void* d_ws, size_t ws_size,
                              hipStream_t stream) {
    const float* h = (const float*)d_in[0];
    float* out = (float*)d_out;

    char* ws = (char*)d_ws;
    unsigned char* hq = (unsigned char*)ws;                      // 4 MB fp8
    size_t off = (size_t)N * D;
    float* norms = (float*)(ws + off);                           // 32 KB
    int* gcnt = (int*)(ws + off + (size_t)N * 4);                // 32 KB
    int* gflag = (int*)(ws + off + (size_t)N * 8);               // 32 KB
    unsigned int* gcand = (unsigned int*)(ws + off + (size_t)N * 12);  // 6 MB

    norm_kernel<<<N / 4, 256, 0, stream>>>(h, hq, norms, gcnt, gflag);
    dim3 grid(64, NSLICE);
    simfp8_kernel<<<grid, 256, 0, stream>>>(hq, gcand, gcnt, gflag);
    gather_kernel<<<N / 4, 256, 0, stream>>>(h, hq, norms, gcand, gcnt, gflag, out);
}

// Round 11
// 162.252 us; speedup vs baseline: 1.1436x; 1.1436x over previous
//
#include <hip/hip_runtime.h>
#include <hip/hip_bf16.h>

#define N 8192
#define D 512
#define K_TOP 12
#define THETA 10.0f
#define EPS 1e-8f
#define NSLICE 16
#define SLICE_J 512    // 4 j-tiles of 128 per block
#define TAU 0.10f      // candidate threshold; spill+fallback guarantee the guard
#define CAPL 14        // per-row per-block LDS cap (overflow -> exact global spill)
#define CAPG 192       // per-row global candidate cap
#define NROUND 32      // 4 jt x 8 ks (K=64 fp8 per round)

typedef float f32x16 __attribute__((ext_vector_type(16)));

__device__ __forceinline__ unsigned int bf16_bits_rne(float v) {
    unsigned int u = __float_as_uint(v);
    u += 0x7FFFu + ((u >> 16) & 1u);
    return u >> 16;
}

// async global->LDS DMA, 16B per lane; LDS dest is wave-uniform base + lane*16
__device__ __forceinline__ void load16(const unsigned char* g, unsigned char* l) {
    __builtin_amdgcn_global_load_lds(
        (const __attribute__((address_space(1))) unsigned int*)g,
        (__attribute__((address_space(3))) unsigned int*)l, 16, 0, 0);
}

// -- Kernel 0: row norms -> fp8 e4m3 normalized copy + norms + zero counters --
__global__ __launch_bounds__(256) void norm_kernel(const float* __restrict__ h,
                                                   unsigned char* __restrict__ hq,
                                                   float* __restrict__ norms,
                                                   int* __restrict__ gcnt,
                                                   int* __restrict__ gflag) {
    int row = blockIdx.x * 4 + (threadIdx.x >> 6);
    int lane = threadIdx.x & 63;
    const float4* hr = (const float4*)(h + (size_t)row * D);
    float4 p0 = hr[lane * 2], p1 = hr[lane * 2 + 1];
    float ss = p0.x * p0.x + p0.y * p0.y + p0.z * p0.z + p0.w * p0.w +
               p1.x * p1.x + p1.y * p1.y + p1.z * p1.z + p1.w * p1.w;
#pragma unroll
    for (int off = 32; off > 0; off >>= 1) ss += __shfl_xor(ss, off, 64);
    float nrm = fmaxf(sqrtf(ss), EPS);
    float inv = 1.0f / nrm;
    if (lane == 0) { gcnt[row] = 0; gflag[row] = 0; norms[row] = nrm; }
    unsigned int w0 = __builtin_amdgcn_cvt_pk_fp8_f32(p0.x * inv, p0.y * inv, 0, false);
    w0 = __builtin_amdgcn_cvt_pk_fp8_f32(p0.z * inv, p0.w * inv, w0, true);
    unsigned int w1 = __builtin_amdgcn_cvt_pk_fp8_f32(p1.x * inv, p1.y * inv, 0, false);
    w1 = __builtin_amdgcn_cvt_pk_fp8_f32(p1.z * inv, p1.w * inv, w1, true);
    ((uint2*)(hq + (size_t)row * D))[lane] = make_uint2(w0, w1);
}

// -- Kernel 1: fp8 MFMA sim tiles, K=64/round, 4 blocks/CU --
// grid (64,16) = 1024 blocks = exactly 4/CU (one generation, no tail).
// Tiles 128 rows x 64 B, double-buffered (32 KB), LDS total 40448 B.
// Swizzle: 16B chunk kk of row r at slot kk ^ ((r>>2)&3) -> b64 reads hit the
// 512B/instr LDS bandwidth floor (4-way = optimal for b64).
__global__ __launch_bounds__(256, 4) void simfp8_kernel(
        const unsigned char* __restrict__ hq,
        unsigned int* __restrict__ gcand,
        int* __restrict__ gcnt,
        int* __restrict__ gflag) {
    __shared__ unsigned char tiles[2][2][128 * 64];  // [sel][A/B] 32 KB
    __shared__ int cnt[128];
    __shared__ unsigned int lbuf[128][CAPL];

    const int i0 = blockIdx.x * 128;
    const int sl = blockIdx.y;
    const int t = threadIdx.x;
    const int wave = t >> 6, lane = t & 63;
    const int wr = (wave >> 1) * 64, wc = (wave & 1) * 64;
    const int lm32 = lane & 31, lg2 = lane >> 5;
    const int rk = (lm32 >> 2) & 3;  // read-side swizzle key ((row>>2)&3)

    // staging: chunk c = e*256 + t (e=0,1); row = c>>2 = e*64 + (t>>2),
    // slot = t&3, source chunk q = slot ^ ((row>>2)&3) = (t&3) ^ ((t>>4)&3)
    const int srow = t >> 2;                 // + e*64
    const int sq = (t & 3) ^ ((t >> 4) & 3);

    if (t < 128) cnt[t] = 0;   // published by first barrier pair

    auto issue = [&](int r) {
        int sel = r & 1;
        int jtn = r >> 3, ksn = r & 7;
        const unsigned char* gA = hq + (size_t)(i0 + srow) * D + ksn * 64 + sq * 16;
        const unsigned char* gB =
            hq + (size_t)(sl * SLICE_J + jtn * 128 + srow) * D + ksn * 64 + sq * 16;
        unsigned char* lA = &tiles[sel][0][t * 16];
        unsigned char* lB = &tiles[sel][1][t * 16];
#pragma unroll
        for (int e = 0; e < 2; e++) {
            load16(gA + (size_t)(e * 64) * D, lA + e * 4096);
            load16(gB + (size_t)(e * 64) * D, lB + e * 4096);
        }
    };

    issue(0);
    f32x16 acc[2][2];

    for (int r = 0; r < NROUND; r++) {
        const int sel = r & 1;
        const int jt = r >> 3, ks = r & 7;
        const int j0 = sl * SLICE_J + jt * 128;

        __builtin_amdgcn_s_barrier();   // prior reads of buffer sel done
        if (r < NROUND - 1) {
            issue(r + 1);
            asm volatile("s_waitcnt vmcnt(4)" ::: "memory");  // drain round r only
        } else {
            asm volatile("s_waitcnt vmcnt(0)" ::: "memory");
        }
        __builtin_amdgcn_s_barrier();   // round r fully in LDS

        if (ks == 0) {
#pragma unroll
            for (int x = 0; x < 2; x++)
#pragma unroll
                for (int y = 0; y < 2; y++)
#pragma unroll
                    for (int q = 0; q < 16; q++) acc[x][y][q] = 0.f;
        }

#pragma unroll
        for (int kk = 0; kk < 4; kk++) {   // 4 x K16 fp8 MFMA steps = K64
            const int kb = ((kk ^ rk) << 4) + lg2 * 8;  // swizzled byte offset
            long long af[2], bfr[2];
#pragma unroll
            for (int x = 0; x < 2; x++)
                af[x] = *(const long long*)&tiles[sel][0][(wr + x * 32 + lm32) * 64 + kb];
#pragma unroll
            for (int y = 0; y < 2; y++)
                bfr[y] = *(const long long*)&tiles[sel][1][(wc + y * 32 + lm32) * 64 + kb];
#pragma unroll
            for (int x = 0; x < 2; x++)
#pragma unroll
                for (int y = 0; y < 2; y++)
                    acc[x][y] = __builtin_amdgcn_mfma_f32_32x32x16_fp8_fp8(
                        af[x], bfr[y], acc[x][y], 0, 0, 0);
        }

        if (ks == 7) {
            // 32x32 C/D: col = lane&31, row = (reg&3) + 8*(reg>>2) + 4*(lane>>5)
#pragma unroll
            for (int x = 0; x < 2; x++)
#pragma unroll
                for (int y = 0; y < 2; y++) {
                    int gcol = j0 + wc + y * 32 + lm32;
#pragma unroll
                    for (int q = 0; q < 16; q++) {
                        int rr = wr + x * 32 + (q & 3) + 8 * (q >> 2) + 4 * lg2;
                        float v = acc[x][y][q];
                        if (i0 + rr == gcol) v = 1.0f;   // exact self-similarity
                        if (v > TAU) {
                            unsigned int e = (bf16_bits_rne(v) << 16) | (unsigned int)gcol;
                            int idx = atomicAdd(&cnt[rr], 1);
                            if (idx < CAPL) lbuf[rr][idx] = e;
                            else {  // rare exact spill straight to global
                                int grow = i0 + rr;
                                int p = atomicAdd(&gcnt[grow], 1);
                                if (p < CAPG) gcand[(size_t)grow * CAPG + p] = e;
                                else gflag[grow] = 1;
                            }
                        }
                    }
                }
        }
    }

    __syncthreads();
    if (t < 128) {
        int c = cnt[t];
        int s = c < CAPL ? c : CAPL;
        if (s > 0) {
            int base = atomicAdd(&gcnt[i0 + t], s);
            unsigned int* dst = gcand + (size_t)(i0 + t) * CAPG;
            for (int k = 0; k < s; k++) {
                int p = base + k;
                if (p < CAPG) dst[p] = lbuf[t][k];
                else gflag[i0 + t] = 1;
            }
        }
    }
}

// -- Kernel 2: exact top-12 + softmax + gather (fp8 neighbors, fp32 self) --
__global__ __launch_bounds__(256) void gather_kernel(const float* __restrict__ h,
                                                     const unsigned char* __restrict__ hq,
                                                     const float* __restrict__ norms,
                                                     const unsigned int* __restrict__ gcand,
                                                     const int* __restrict__ gcnt,
                                                     const int* __restrict__ gflag,
                                                     float* __restrict__ out) {
    int row = blockIdx.x * 4 + (threadIdx.x >> 6);
    int lane = threadIdx.x & 63;
    int c = gcnt[row];

    float selv[K_TOP];
    int selj[K_TOP];

    if (c >= K_TOP && c <= CAPG && gflag[row] == 0) {
        const unsigned int* cr = gcand + (size_t)row * CAPG;
        unsigned int e[3];
#pragma unroll
        for (int q = 0; q < 3; q++) {
            int idx = lane + 64 * q;
            e[q] = (idx < c) ? cr[idx] : 0u;
        }
#pragma unroll
        for (int k = 0; k < K_TOP; k++) {
            unsigned int m = e[0];
            if (e[1] > m) m = e[1];
            if (e[2] > m) m = e[2];
#pragma unroll
            for (int off = 32; off > 0; off >>= 1) {
                unsigned int om = __shfl_xor(m, off, 64);
                if (om > m) m = om;
            }
            selv[k] = __uint_as_float(m & 0xFFFF0000u);
            selj[k] = (int)(m & 0x1FFFu);
#pragma unroll
            for (int q = 0; q < 3; q++)
                if (e[q] == m) e[q] = 0u;   // entries unique (distinct cols)
        }
    } else {
        // exact brute-force fallback over fp8 rows (rare; cheap insurance)
        float vals[K_TOP];
        int idxs[K_TOP];
#pragma unroll
        for (int q = 0; q < K_TOP; q++) { vals[q] = -3e38f; idxs[q] = 0; }
        float minv = -3e38f;
        int minp = 0;
        const unsigned int* rp = (const unsigned int*)(hq + (size_t)row * D);
        for (int col = lane; col < N; col += 64) {
            const unsigned int* cp = (const unsigned int*)(hq + (size_t)col * D);
            float s = 0.f;
            for (int k4 = 0; k4 < D / 4; k4++) {
                unsigned int ra = rp[k4], ca = cp[k4];
                s += __builtin_amdgcn_cvt_f32_fp8(ra, 0) * __builtin_amdgcn_cvt_f32_fp8(ca, 0);
                s += __builtin_amdgcn_cvt_f32_fp8(ra, 1) * __builtin_amdgcn_cvt_f32_fp8(ca, 1);
                s += __builtin_amdgcn_cvt_f32_fp8(ra, 2) * __builtin_amdgcn_cvt_f32_fp8(ca, 2);
                s += __builtin_amdgcn_cvt_f32_fp8(ra, 3) * __builtin_amdgcn_cvt_f32_fp8(ca, 3);
            }
            if (col == row) s = 1.0f;
            if (s > minv) {
                vals[minp] = s; idxs[minp] = col;
                minv = vals[0]; minp = 0;
#pragma unroll
                for (int q = 1; q < K_TOP; q++)
                    if (vals[q] < minv) { minv = vals[q]; minp = q; }
            }
        }
        for (int k = 0; k < K_TOP; k++) {
            float bv = vals[0]; int bp = 0;
#pragma unroll
            for (int q = 1; q < K_TOP; q++)
                if (vals[q] > bv) { bv = vals[q]; bp = q; }
            float v = bv; int j = idxs[bp]; int src = lane;
#pragma unroll
            for (int off = 32; off > 0; off >>= 1) {
                float ov = __shfl_xor(v, off, 64);
                int oj = __shfl_xor(j, off, 64);
                int os = __shfl_xor(src, off, 64);
                if (ov > v || (ov == v && os < src)) { v = ov; j = oj; src = os; }
            }
            selv[k] = __uint_as_float((unsigned int)(bf16_bits_rne(v) << 16));
            selj[k] = j;
            if (lane == src) vals[bp] = -3e38f;
        }
    }

    float mx = selv[0];
    float beta[K_TOP];
    float sum = 0.f;
#pragma unroll
    for (int q = 0; q < K_TOP; q++) { beta[q] = __expf(THETA * (selv[q] - mx)); sum += beta[q]; }
    float rs = 1.0f / sum;

    // lane owns output elements [lane*8, lane*8+8)
    float acc[8];
#pragma unroll
    for (int ee = 0; ee < 8; ee++) acc[ee] = 0.f;
#pragma unroll
    for (int q = 0; q < K_TOP; q++) {
        int j = selj[q];
        float w = beta[q] * rs;
        if (j == row) {   // wave-uniform; dominant term stays fp32-exact
            const float4* hr = (const float4*)(h + (size_t)row * D);
            float4 p0 = hr[lane * 2], p1 = hr[lane * 2 + 1];
            acc[0] += w * p0.x; acc[1] += w * p0.y; acc[2] += w * p0.z; acc[3] += w * p0.w;
            acc[4] += w * p1.x; acc[5] += w * p1.y; acc[6] += w * p1.z; acc[7] += w * p1.w;
        } else {          // neighbors (weight ~2e-4): fp8 row x norm
            float wj = w * norms[j];
            uint2 hv = ((const uint2*)(hq + (size_t)j * D))[lane];
            acc[0] += wj * __builtin_amdgcn_cvt_f32_fp8(hv.x, 0);
            acc[1] += wj * __builtin_amdgcn_cvt_f32_fp8(hv.x, 1);
            acc[2] += wj * __builtin_amdgcn_cvt_f32_fp8(hv.x, 2);
            acc[3] += wj * __builtin_amdgcn_cvt_f32_fp8(hv.x, 3);
            acc[4] += wj * __builtin_amdgcn_cvt_f32_fp8(hv.y, 0);
            acc[5] += wj * __builtin_amdgcn_cvt_f32_fp8(hv.y, 1);
            acc[6] += wj * __builtin_amdgcn_cvt_f32_fp8(hv.y, 2);
            acc[7] += wj * __builtin_amdgcn_cvt_f32_fp8(hv.y, 3);
        }
    }
    float4* orow = (float4*)(out + (size_t)row * D);
    orow[lane * 2] = make_float4(acc[0], acc[1], acc[2], acc[3]);
    orow[lane * 2 + 1] = make_float4(acc[4], acc[5], acc[6], acc[7]);
}

extern "C" void kernel_launch(void* const* d_in, const int* in_sizes, int n_in,
                              void* d_out, int out_size, void* d_ws, size_t ws_size,
                              hipStream_t stream) {
    const float* h = (const float*)d_in[0];
    float* out = (float*)d_out;

    char* ws = (char*)d_ws;
    unsigned char* hq = (unsigned char*)ws;                      // 4 MB fp8
    size_t off = (size_t)N * D;
    float* norms = (float*)(ws + off);                           // 32 KB
    int* gcnt = (int*)(ws + off + (size_t)N * 4);                // 32 KB
    int* gflag = (int*)(ws + off + (size_t)N * 8);               // 32 KB
    unsigned int* gcand = (unsigned int*)(ws + off + (size_t)N * 12);  // 6 MB

    norm_kernel<<<N / 4, 256, 0, stream>>>(h, hq, norms, gcnt, gflag);
    dim3 grid(64, NSLICE);
    simfp8_kernel<<<grid, 256, 0, stream>>>(hq, gcand, gcnt, gflag);
    gather_kernel<<<N / 4, 256, 0, stream>>>(h, hq, norms, gcand, gcnt, gflag, out);
}